// Round 2
// baseline (4992.345 us; speedup 1.0000x reference)
//
#include <hip/hip_runtime.h>
#include <hip/hip_bf16.h>

#define B_   16
#define NB   1024
#define NS   4096
#define C_   768
#define H_   12
#define DH   64
#define KTOP 128
#define POOL 192
#define CM   3072
#define EPSV 1e-5f

typedef __hip_bfloat16 bf16;
typedef __attribute__((ext_vector_type(8))) short short8;
typedef __attribute__((ext_vector_type(4))) float f32x4;

__device__ __forceinline__ float bf2f(unsigned short s){
  union{unsigned int u; float f;} v; v.u = ((unsigned int)s)<<16; return v.f;
}
__device__ __forceinline__ unsigned short f2bf_bits(float x){
  union { bf16 b; unsigned short u; } t; t.b = __float2bfloat16(x); return t.u;
}

template<typename T> __device__ __forceinline__ float4 load4(const T* p);
template<> __device__ __forceinline__ float4 load4<float>(const float* p){ return *(const float4*)p; }
template<> __device__ __forceinline__ float4 load4<bf16>(const bf16* p){
  ushort4 u = *(const ushort4*)p;
  return make_float4(bf2f(u.x), bf2f(u.y), bf2f(u.z), bf2f(u.w));
}
template<typename T> __device__ __forceinline__ void store4(T* p, float4 v);
template<> __device__ __forceinline__ void store4<float>(float* p, float4 v){ *(float4*)p = v; }
template<> __device__ __forceinline__ void store4<bf16>(bf16* p, float4 v){
  union{ ushort4 u; bf16 h[4]; } t;
  t.h[0] = __float2bfloat16(v.x); t.h[1] = __float2bfloat16(v.y);
  t.h[2] = __float2bfloat16(v.z); t.h[3] = __float2bfloat16(v.w);
  *(ushort4*)p = t.u;
}

__device__ __forceinline__ float gelu_exact(float x){
  return 0.5f * x * (1.0f + erff(x * 0.70710678118654752f));
}

__device__ __forceinline__ void gl2lds16(const unsigned short* g, unsigned short* l){
  __builtin_amdgcn_global_load_lds(
      (const __attribute__((address_space(1))) unsigned int*)g,
      (__attribute__((address_space(3))) unsigned int*)l, 16, 0, 0);
}

// ---------------------------------------------------------------------------
// fp32 -> bf16 hi/lo split (round-to-nearest; lo = x - hi)
// ---------------------------------------------------------------------------
__global__ __launch_bounds__(256) void conv_hilo(
    const float* __restrict__ src, unsigned short* __restrict__ hi,
    unsigned short* __restrict__ lo, int n4)
{
  int i = blockIdx.x*256 + threadIdx.x;
  if (i >= n4) return;
  float4 v = ((const float4*)src)[i];
  ushort4 h, l;
  h.x = f2bf_bits(v.x); l.x = f2bf_bits(v.x - bf2f(h.x));
  h.y = f2bf_bits(v.y); l.y = f2bf_bits(v.y - bf2f(h.y));
  h.z = f2bf_bits(v.z); l.z = f2bf_bits(v.z - bf2f(h.z));
  h.w = f2bf_bits(v.w); l.w = f2bf_bits(v.w - bf2f(h.w));
  ((ushort4*)hi)[i] = h;
  ((ushort4*)lo)[i] = l;
}

// ---------------------------------------------------------------------------
// Saliency via 3-term bf16-split MFMA, fused row-max.
// Block: 128 sampled rows x 128 base rows, K=768. grid (nc=8, rc=32, bl=8).
// part[b][row][nc] = max_{n in chunk} dot (raw, unscaled, fp32 approx)
// ---------------------------------------------------------------------------
__global__ __launch_bounds__(256) void saliency_mfma(
    const unsigned short* __restrict__ s_hi, const unsigned short* __restrict__ s_lo,
    const unsigned short* __restrict__ b_hi, const unsigned short* __restrict__ b_lo,
    float* __restrict__ part, int b_off)
{
  const int nc = blockIdx.x;
  const int rc = blockIdx.y;
  const int bl = blockIdx.z;
  __shared__ unsigned short Ah[128*32], Al[128*32], Bh[128*32], Bl[128*32];
  __shared__ float red[2][2][64];
  const int tid  = threadIdx.x;
  const int wave = tid >> 6, lane = tid & 63;
  const int wm = wave >> 1, wn = wave & 1;
  const int quad = lane >> 4, l16 = lane & 15;

  const size_t sbase = ((size_t)bl*NS + (size_t)rc*128) * C_;
  const size_t bbase = ((size_t)bl*NB + (size_t)nc*128) * C_;

  f32x4 acc[4][4];
#pragma unroll
  for (int i=0;i<4;i++)
#pragma unroll
    for (int j=0;j<4;j++) acc[i][j] = (f32x4){0.f,0.f,0.f,0.f};

  // staging roles: wave0->Ah, wave1->Al, wave2->Bh, wave3->Bl
  const unsigned short* gsrc;
  unsigned short* ldst;
  size_t gbase;
  if      (wave==0){ gsrc = s_hi; ldst = Ah; gbase = sbase; }
  else if (wave==1){ gsrc = s_lo; ldst = Al; gbase = sbase; }
  else if (wave==2){ gsrc = b_hi; ldst = Bh; gbase = bbase; }
  else             { gsrc = b_lo; ldst = Bl; gbase = bbase; }
  const int rl = lane >> 2, c8 = (lane & 3) * 8;

  for (int k0 = 0; k0 < C_; k0 += 32){
#pragma unroll
    for (int sub=0; sub<8; sub++){
      gl2lds16(gsrc + gbase + (size_t)(sub*16 + rl)*C_ + k0 + c8,
               ldst + sub*512 + lane*8);
    }
    __syncthreads();

    short8 ah[4], al[4], bh[4], bl[4];
#pragma unroll
    for (int f=0; f<4; f++){
      const int ar = wm*64 + f*16 + l16;
      ah[f] = *(const short8*)(Ah + ar*32 + quad*8);
      al[f] = *(const short8*)(Al + ar*32 + quad*8);
      const int br = wn*64 + f*16 + l16;
      bh[f] = *(const short8*)(Bh + br*32 + quad*8);
      bl[f] = *(const short8*)(Bl + br*32 + quad*8);
    }
#pragma unroll
    for (int i=0;i<4;i++)
#pragma unroll
      for (int j=0;j<4;j++){
        acc[i][j] = __builtin_amdgcn_mfma_f32_16x16x32_bf16(ah[i], bh[j], acc[i][j], 0,0,0);
        acc[i][j] = __builtin_amdgcn_mfma_f32_16x16x32_bf16(ah[i], bl[j], acc[i][j], 0,0,0);
        acc[i][j] = __builtin_amdgcn_mfma_f32_16x16x32_bf16(al[i], bh[j], acc[i][j], 0,0,0);
      }
    __syncthreads();
  }

  // row-max epilogue. C/D: col=lane&15, row=quad*4+reg
  float rmax[4][4];
#pragma unroll
  for (int fm=0; fm<4; fm++)
#pragma unroll
    for (int rg=0; rg<4; rg++){
      float m = acc[fm][0][rg];
      m = fmaxf(m, acc[fm][1][rg]);
      m = fmaxf(m, acc[fm][2][rg]);
      m = fmaxf(m, acc[fm][3][rg]);
#pragma unroll
      for (int off=1; off<16; off<<=1) m = fmaxf(m, __shfl_xor(m, off));
      rmax[fm][rg] = m;
    }
  if (l16 == 0){
#pragma unroll
    for (int fm=0; fm<4; fm++)
#pragma unroll
      for (int rg=0; rg<4; rg++)
        red[wm][wn][fm*16 + quad*4 + rg] = rmax[fm][rg];
  }
  __syncthreads();
  if (tid < 128){
    const int wmx = tid >> 6, rr = tid & 63;
    float v = fmaxf(red[wmx][0][rr], red[wmx][1][rr]);
    const int grow = rc*128 + wmx*64 + rr;
    part[(((size_t)(b_off+bl))*NS + grow)*8 + nc] = v;
  }
}

__global__ __launch_bounds__(256) void reduce_rowmax(
    const float* __restrict__ part, float* __restrict__ sc)
{
  int i = blockIdx.x*256 + threadIdx.x;   // 0..B*NS-1
  const float* p = part + (size_t)i*8;
  float m = p[0];
#pragma unroll
  for (int t=1;t<8;t++) m = fmaxf(m, p[t]);
  sc[i] = m * 0.036084391824351615f;  // 1/sqrt(768)
}

// ---------------------------------------------------------------------------
// Approx top-POOL (192) per batch by iterative argmax on fp32 approx scores.
// ---------------------------------------------------------------------------
__global__ __launch_bounds__(256) void pool_topk(
    const float* __restrict__ sc, int* __restrict__ pool_i)
{
  const int b = blockIdx.x, tid = threadIdx.x;
  __shared__ float vals[NS];
  __shared__ float wv_s[4]; __shared__ int wi_s[4];
  for (int e=0;e<NS/256;e++) vals[e*256+tid] = sc[(size_t)b*NS + e*256+tid];
  __syncthreads();
  for (int iter=0; iter<POOL; iter++){
    float bv = -1e30f; int bi = 0x7fffffff;
    for (int e=0;e<NS/256;e++){
      int idx = e*256+tid; float v = vals[idx];
      if (v > bv){ bv=v; bi=idx; }
    }
    for (int off=32; off>=1; off>>=1){
      float ov = __shfl_down(bv, off);
      int    oi = __shfl_down(bi, off);
      if (ov > bv || (ov == bv && oi < bi)){ bv=ov; bi=oi; }
    }
    const int lane = tid & 63, w = tid >> 6;
    if (lane==0){ wv_s[w]=bv; wi_s[w]=bi; }
    __syncthreads();
    if (tid==0){
      float fv = wv_s[0]; int fi = wi_s[0];
      for (int t=1;t<4;t++) if (wv_s[t] > fv || (wv_s[t]==fv && wi_s[t]<fi)){ fv=wv_s[t]; fi=wi_s[t]; }
      pool_i[b*POOL + iter] = fi; vals[fi] = -1e30f;
    }
    __syncthreads();
  }
}

// ---------------------------------------------------------------------------
// Exact fp64 rescore of pool rows. grid (rq=4, pg=12, b=16).
// Block: 16 cands x 256 base rows -> dpart[(b*POOL+p)*4 + rq] = partial max.
// ---------------------------------------------------------------------------
__global__ __launch_bounds__(256) void rescore(
    const float* __restrict__ sampled, const float* __restrict__ base,
    const int* __restrict__ pool_i, double* __restrict__ dpart)
{
  const int rq = blockIdx.x, pg = blockIdx.y, b = blockIdx.z;
  __shared__ float cand[16][768];
  __shared__ double red[16][16];
  const int tid = threadIdx.x;
  const int c = tid >> 4, r = tid & 15;

  {
    const int cs = tid >> 4, seg = tid & 15;
    const int idx = pool_i[b*POOL + pg*16 + cs];
    const float4* src = (const float4*)(sampled + ((size_t)b*NS + idx)*C_ + seg*48);
    float4* dst = (float4*)(&cand[cs][seg*48]);
#pragma unroll
    for (int j=0;j<12;j++) dst[j] = src[j];
  }
  __syncthreads();

  double best = -1e300;
  for (int i=0;i<16;i++){
    const int row = rq*256 + i*16 + r;
    const float4* bp = (const float4*)(base + ((size_t)b*NB + row)*C_);
    const float4* cp = (const float4*)(&cand[c][0]);
    double acc = 0.0;
    for (int k=0;k<192;k++){
      float4 bv = bp[k]; float4 cv = cp[k];
      acc = fma((double)bv.x, (double)cv.x, acc);
      acc = fma((double)bv.y, (double)cv.y, acc);
      acc = fma((double)bv.z, (double)cv.z, acc);
      acc = fma((double)bv.w, (double)cv.w, acc);
    }
    best = fmax(best, acc);
  }
  red[c][r] = best;
  __syncthreads();
  if (r == 0){
    double m = red[c][0];
#pragma unroll
    for (int t=1;t<16;t++) m = fmax(m, red[c][t]);
    dpart[((size_t)b*POOL + pg*16 + c)*4 + rq] = m;
  }
}

// ---------------------------------------------------------------------------
// Exact top-128 from the 192-pool (fp64 values, tie-break lowest orig index).
// ---------------------------------------------------------------------------
__global__ __launch_bounds__(256) void final_topk(
    const double* __restrict__ dpart, const int* __restrict__ pool_i,
    float* __restrict__ o_topk, int* __restrict__ topk_i)
{
  const int b = blockIdx.x, tid = threadIdx.x;
  __shared__ double dv[POOL];
  __shared__ int di[POOL];
  __shared__ double wv_s[4]; __shared__ int wi_s[4], ws_s[4];
  if (tid < POOL){
    const double* p = dpart + ((size_t)b*POOL + tid)*4;
    double m = fmax(fmax(p[0],p[1]), fmax(p[2],p[3]));
    dv[tid] = m / 27.712812921102035;   // sqrt(768)
    di[tid] = pool_i[b*POOL + tid];
  }
  __syncthreads();
  for (int iter=0; iter<KTOP; iter++){
    double bv = -1e300; int bi = 0x7fffffff; int bs = -1;
    if (tid < POOL){ bv = dv[tid]; bi = di[tid]; bs = tid; }
    for (int off=32; off>=1; off>>=1){
      double ov = __shfl_down(bv, off);
      int oi = __shfl_down(bi, off);
      int os = __shfl_down(bs, off);
      if (ov > bv || (ov == bv && oi < bi)){ bv=ov; bi=oi; bs=os; }
    }
    const int lane = tid & 63, w = tid >> 6;
    if (lane==0){ wv_s[w]=bv; wi_s[w]=bi; ws_s[w]=bs; }
    __syncthreads();
    if (tid==0){
      double fv = wv_s[0]; int fi = wi_s[0]; int fs = ws_s[0];
      for (int t=1;t<4;t++)
        if (wv_s[t] > fv || (wv_s[t]==fv && wi_s[t]<fi)){ fv=wv_s[t]; fi=wi_s[t]; fs=ws_s[t]; }
      o_topk[(size_t)b*KTOP + iter] = (float)fi;
      topk_i[b*KTOP + iter] = fi;
      dv[fs] = -1e300;
    }
    __syncthreads();
  }
}

__global__ __launch_bounds__(192) void gather_kernel(
    const float* __restrict__ sampled, const int* __restrict__ topk_i, float* __restrict__ sel)
{
  const int blk = blockIdx.x; const int b = blk >> 7, kk = blk & 127;
  const int idx = topk_i[b*KTOP + kk];
  const float4* src = (const float4*)(sampled + ((size_t)b*NS + idx)*C_);
  float4* dst = (float4*)(sel + ((size_t)b*KTOP + kk)*C_);
  dst[threadIdx.x] = src[threadIdx.x];
}

// ---------------------------------------------------------------------------
// Generic tiled GEMM (unchanged from round 1)
// ---------------------------------------------------------------------------
template<typename TIN, typename TOUT, int ACT, bool RES>
__global__ __launch_bounds__(256) void gemm_tile(
    const TIN* __restrict__ A, const float* __restrict__ W,
    const float* __restrict__ bias, const float* __restrict__ res,
    TOUT* __restrict__ out, int M, int N, int K)
{
  __shared__ float As[16][68];
  __shared__ float Bs[16][68];
  const int tid = threadIdx.x;
  const int tx = tid & 15, ty = tid >> 4;
  const int m0 = blockIdx.y * 64, n0 = blockIdx.x * 64;
  const int am = tid >> 2, ak = (tid & 3) * 4;
  const int bk = tid >> 4, bn = (tid & 15) * 4;
  float c[4][4] = {{0.f,0.f,0.f,0.f},{0.f,0.f,0.f,0.f},{0.f,0.f,0.f,0.f},{0.f,0.f,0.f,0.f}};

  for (int k0 = 0; k0 < K; k0 += 16){
    float4 a4 = load4<TIN>(A + (size_t)(m0+am)*K + (k0+ak));
    As[ak+0][am]=a4.x; As[ak+1][am]=a4.y; As[ak+2][am]=a4.z; As[ak+3][am]=a4.w;
    float4 b4 = *(const float4*)(W + (size_t)(k0+bk)*N + (n0+bn));
    *(float4*)&Bs[bk][bn] = b4;
    __syncthreads();
#pragma unroll
    for (int kk=0; kk<16; kk++){
      const float4 a = *(const float4*)&As[kk][ty*4];
      const float4 b = *(const float4*)&Bs[kk][tx*4];
      const float av[4] = {a.x,a.y,a.z,a.w};
      const float bw[4] = {b.x,b.y,b.z,b.w};
#pragma unroll
      for (int i=0;i<4;i++)
#pragma unroll
        for (int j=0;j<4;j++)
          c[i][j] = fmaf(av[i], bw[j], c[i][j]);
    }
    __syncthreads();
  }

  const float4 bv = *(const float4*)(bias + n0 + tx*4);
#pragma unroll
  for (int i=0;i<4;i++){
    const size_t row = (size_t)(m0 + ty*4 + i);
    float4 v = make_float4(c[i][0]+bv.x, c[i][1]+bv.y, c[i][2]+bv.z, c[i][3]+bv.w);
    if (RES){
      const float4 r = *(const float4*)(res + row*N + n0 + tx*4);
      v.x+=r.x; v.y+=r.y; v.z+=r.z; v.w+=r.w;
    }
    if (ACT==1){ v.x=gelu_exact(v.x); v.y=gelu_exact(v.y); v.z=gelu_exact(v.z); v.w=gelu_exact(v.w); }
    store4<TOUT>(out + row*N + n0 + tx*4, v);
  }
}

// ---------------------------------------------------------------------------
// Attention (unchanged from round 1)
// ---------------------------------------------------------------------------
__global__ __launch_bounds__(256) void attn_softmax(
    const bf16* __restrict__ q, const float* __restrict__ kbuf, float* __restrict__ attn)
{
  const int qt = blockIdx.x, h = blockIdx.y, b = blockIdx.z;
  __shared__ float As[16][68];
  __shared__ float Bs[16][132];
  const int tid = threadIdx.x;
  const int tx = tid & 31, ty = tid >> 5;
  const int am = tid >> 2, ak = (tid & 3)*4;
  const int bm = tid >> 1, bk = (tid & 1)*8;
  float c[8][4] = {{0.f,0.f,0.f,0.f},{0.f,0.f,0.f,0.f},{0.f,0.f,0.f,0.f},{0.f,0.f,0.f,0.f},
                   {0.f,0.f,0.f,0.f},{0.f,0.f,0.f,0.f},{0.f,0.f,0.f,0.f},{0.f,0.f,0.f,0.f}};

  for (int k0 = 0; k0 < DH; k0 += 16){
    float4 a4 = load4<bf16>(q + ((size_t)(b*NB + qt*64 + am))*C_ + h*DH + k0 + ak);
    As[ak+0][am]=a4.x; As[ak+1][am]=a4.y; As[ak+2][am]=a4.z; As[ak+3][am]=a4.w;
    const float* kp = kbuf + ((size_t)(b*KTOP + bm))*C_ + h*DH + k0 + bk;
    float4 b40 = *(const float4*)(kp);
    float4 b41 = *(const float4*)(kp + 4);
    Bs[bk+0][bm]=b40.x; Bs[bk+1][bm]=b40.y; Bs[bk+2][bm]=b40.z; Bs[bk+3][bm]=b40.w;
    Bs[bk+4][bm]=b41.x; Bs[bk+5][bm]=b41.y; Bs[bk+6][bm]=b41.z; Bs[bk+7][bm]=b41.w;
    __syncthreads();
#pragma unroll
    for (int kk=0; kk<16; kk++){
      const float4 a0 = *(const float4*)&As[kk][ty*8];
      const float4 a1 = *(const float4*)&As[kk][ty*8+4];
      const float4 bb = *(const float4*)&Bs[kk][tx*4];
      const float av[8] = {a0.x,a0.y,a0.z,a0.w,a1.x,a1.y,a1.z,a1.w};
      const float bw[4] = {bb.x,bb.y,bb.z,bb.w};
#pragma unroll
      for (int i=0;i<8;i++)
#pragma unroll
        for (int j=0;j<4;j++)
          c[i][j] = fmaf(av[i], bw[j], c[i][j]);
    }
    __syncthreads();
  }

  const float scale = 0.125f;
  const size_t obase = (((size_t)b*H_ + h)*NB + (size_t)qt*64)*KTOP;
#pragma unroll
  for (int i=0;i<8;i++){
    float l[4];
#pragma unroll
    for (int j=0;j<4;j++) l[j] = c[i][j]*scale;
    float m = fmaxf(fmaxf(l[0],l[1]), fmaxf(l[2],l[3]));
    for (int off=16; off>=1; off>>=1) m = fmaxf(m, __shfl_xor(m, off, 32));
    float p[4]; float s = 0.f;
#pragma unroll
    for (int j=0;j<4;j++){ p[j] = expf(l[j]-m); s += p[j]; }
    for (int off=16; off>=1; off>>=1) s += __shfl_xor(s, off, 32);
    const float inv = 1.0f / s;
    float4 o = make_float4(p[0]*inv, p[1]*inv, p[2]*inv, p[3]*inv);
    *(float4*)(attn + obase + (size_t)(ty*8+i)*KTOP + tx*4) = o;
  }
}

__global__ __launch_bounds__(256) void attn_pv(
    const float* __restrict__ attn, const float* __restrict__ vbuf, bf16* __restrict__ attout)
{
  const int qt = blockIdx.x, h = blockIdx.y, b = blockIdx.z;
  __shared__ float As[16][68];
  __shared__ float Bs[16][68];
  const int tid = threadIdx.x;
  const int tx = tid & 15, ty = tid >> 4;
  const int am = tid >> 2, ak = (tid & 3)*4;
  const int bk = tid >> 4, bn = (tid & 15)*4;
  const float* Ab = attn + (((size_t)b*H_ + h)*NB + (size_t)qt*64)*KTOP;
  float c[4][4] = {{0.f,0.f,0.f,0.f},{0.f,0.f,0.f,0.f},{0.f,0.f,0.f,0.f},{0.f,0.f,0.f,0.f}};

  for (int k0 = 0; k0 < KTOP; k0 += 16){
    float4 a4 = *(const float4*)(Ab + (size_t)am*KTOP + k0 + ak);
    As[ak+0][am]=a4.x; As[ak+1][am]=a4.y; As[ak+2][am]=a4.z; As[ak+3][am]=a4.w;
    float4 b4 = *(const float4*)(vbuf + ((size_t)(b*KTOP + k0 + bk))*C_ + h*DH + bn);
    *(float4*)&Bs[bk][bn] = b4;
    __syncthreads();
#pragma unroll
    for (int kk=0; kk<16; kk++){
      const float4 a = *(const float4*)&As[kk][ty*4];
      const float4 bb = *(const float4*)&Bs[kk][tx*4];
      const float av[4] = {a.x,a.y,a.z,a.w};
      const float bw[4] = {bb.x,bb.y,bb.z,bb.w};
#pragma unroll
      for (int i=0;i<4;i++)
#pragma unroll
        for (int j=0;j<4;j++)
          c[i][j] = fmaf(av[i], bw[j], c[i][j]);
    }
    __syncthreads();
  }
#pragma unroll
  for (int i=0;i<4;i++){
    float4 v = make_float4(c[i][0], c[i][1], c[i][2], c[i][3]);
    store4<bf16>(attout + ((size_t)(b*NB + qt*64 + ty*4 + i))*C_ + h*DH + tx*4, v);
  }
}

__global__ __launch_bounds__(256) void ln_kernel(
    const float* __restrict__ inA, const float* __restrict__ inB,
    const float* __restrict__ g, const float* __restrict__ bb, float* __restrict__ out)
{
  const int row = blockIdx.x, tid = threadIdx.x;
  const size_t base = (size_t)row * C_;
  float x[3];
#pragma unroll
  for (int e=0;e<3;e++){
    const int idx = e*256 + tid;
    x[e] = inA[base+idx] + (inB ? inB[base+idx] : 0.f);
  }
  float s1 = x[0]+x[1]+x[2];
  float s2 = x[0]*x[0]+x[1]*x[1]+x[2]*x[2];
  for (int off=32; off>=1; off>>=1){ s1 += __shfl_down(s1,off); s2 += __shfl_down(s2,off); }
  __shared__ float a1[4], a2[4], st[2];
  const int lane = tid & 63, w = tid >> 6;
  if (lane==0){ a1[w]=s1; a2[w]=s2; }
  __syncthreads();
  if (tid==0){
    float t1 = a1[0]+a1[1]+a1[2]+a1[3];
    float t2 = a2[0]+a2[1]+a2[2]+a2[3];
    float mu = t1 * (1.0f/C_);
    float var = t2 * (1.0f/C_) - mu*mu;
    st[0]=mu; st[1]=rsqrtf(var + EPSV);
  }
  __syncthreads();
  const float mu = st[0], rs = st[1];
#pragma unroll
  for (int e=0;e<3;e++){
    const int idx = e*256+tid;
    out[base+idx] = (x[e]-mu)*rs*g[idx] + bb[idx];
  }
}

// ---------------------------------------------------------------------------
extern "C" void kernel_launch(void* const* d_in, const int* in_sizes, int n_in,
                              void* d_out, int out_size, void* d_ws, size_t ws_size,
                              hipStream_t stream)
{
  const float* base    = (const float*)d_in[0];
  const float* sampled = (const float*)d_in[1];
  const float* Wq = (const float*)d_in[2];  const float* bq = (const float*)d_in[3];
  const float* Wk = (const float*)d_in[4];  const float* bk = (const float*)d_in[5];
  const float* Wv = (const float*)d_in[6];  const float* bv = (const float*)d_in[7];
  const float* Wo = (const float*)d_in[8];  const float* bo = (const float*)d_in[9];
  const float* g1 = (const float*)d_in[10]; const float* b1 = (const float*)d_in[11];
  const float* g2 = (const float*)d_in[12]; const float* b2 = (const float*)d_in[13];
  const float* Wm1 = (const float*)d_in[14]; const float* bm1 = (const float*)d_in[15];
  const float* Wm2 = (const float*)d_in[16]; const float* bm2 = (const float*)d_in[17];

  float* out = (float*)d_out;
  float* o_x      = out;                 // [16,1024,768]
  float* o_scores = out + 12582912;      // [16,4096]
  float* o_attn   = out + 12648448;      // [16,12,1024,128]
  float* o_topk   = out + 37814272;      // [16,128] (as float)
  float* o_sel    = out + 37816320;      // [16,128,768]

  char* ws = (char*)d_ws;
  // region A: small persistents
  int*    pool_i = (int*)   (ws);                 // 12 KB
  int*    topk_i = (int*)   (ws + 12288);         // 8 KB
  double* dpart  = (double*)(ws + 20480);         // 96 KB
  // region X (time-shared), base at 256 KB
  char* X = ws + 262144;
  // phase 1 (saliency, half-batch):
  unsigned short* s_hi = (unsigned short*)(X);
  unsigned short* s_lo = (unsigned short*)(X + 50331648);
  unsigned short* bh_  = (unsigned short*)(X + 100663296);
  unsigned short* bl_  = (unsigned short*)(X + 113246208);
  float*          part = (float*)        (X + 134217728);   // 2 MB, [16][4096][8]
  // phase 2 (attention/MLP):
  float* kbuf   = (float*)(X);                    // 6.29 MB
  float* vbuf   = (float*)(X + 6291456);          // 6.29 MB
  bf16*  qbuf   = (bf16*) (X + 12582912);         // 25.2 MB
  bf16*  attbuf = (bf16*) (X + 37748736);         // 25.2 MB
  float* rbuf   = (float*)(X + 62914560);         // 50.3 MB
  bf16*  hbuf   = (bf16*) (X + 113246208);        // 100.7 MB -> end ~214.2 MB

  const int HB = 8;                               // batches per half
  const int sh_n4 = HB*NS*C_/4, bh_n4 = HB*NB*C_/4;

  // ---- saliency phase (two half-batches through shared bf16 buffers) ----
  for (int h=0; h<2; h++){
    const int b0 = h*HB;
    conv_hilo<<<(sh_n4+255)/256, 256, 0, stream>>>(sampled + (size_t)b0*NS*C_, s_hi, s_lo, sh_n4);
    conv_hilo<<<(bh_n4+255)/256, 256, 0, stream>>>(base + (size_t)b0*NB*C_, bh_, bl_, bh_n4);
    saliency_mfma<<<dim3(8, 32, HB), 256, 0, stream>>>(s_hi, s_lo, bh_, bl_, part, b0);
  }
  reduce_rowmax<<<(B_*NS)/256, 256, 0, stream>>>(part, o_scores);
  pool_topk<<<B_, 256, 0, stream>>>(o_scores, pool_i);
  rescore<<<dim3(4, POOL/16, B_), 256, 0, stream>>>(sampled, base, pool_i, dpart);
  final_topk<<<B_, 256, 0, stream>>>(dpart, pool_i, o_topk, topk_i);
  gather_kernel<<<B_*KTOP, 192, 0, stream>>>(sampled, topk_i, o_sel);

  // ---- attention + MLP phase ----
  gemm_tile<float, bf16, 0, false><<<dim3(C_/64, (B_*NB)/64), 256, 0, stream>>>(base, Wq, bq, nullptr, qbuf, B_*NB, C_, C_);
  gemm_tile<float, float, 0, false><<<dim3(C_/64, (B_*KTOP)/64), 256, 0, stream>>>(o_sel, Wk, bk, nullptr, kbuf, B_*KTOP, C_, C_);
  gemm_tile<float, float, 0, false><<<dim3(C_/64, (B_*KTOP)/64), 256, 0, stream>>>(o_sel, Wv, bv, nullptr, vbuf, B_*KTOP, C_, C_);
  attn_softmax<<<dim3(NB/64, H_, B_), 256, 0, stream>>>(qbuf, kbuf, o_attn);
  attn_pv<<<dim3(NB/64, H_, B_), 256, 0, stream>>>(o_attn, vbuf, attbuf);
  gemm_tile<bf16, float, 0, true><<<dim3(C_/64, (B_*NB)/64), 256, 0, stream>>>(attbuf, Wo, bo, base, rbuf, B_*NB, C_, C_);
  ln_kernel<<<B_*NB, 256, 0, stream>>>(rbuf, nullptr, g1, b1, o_x);
  gemm_tile<float, bf16, 1, false><<<dim3(CM/64, (B_*NB)/64), 256, 0, stream>>>(o_x, Wm1, bm1, nullptr, hbuf, B_*NB, CM, C_);
  gemm_tile<bf16, float, 0, false><<<dim3(C_/64, (B_*NB)/64), 256, 0, stream>>>(hbuf, Wm2, bm2, nullptr, rbuf, B_*NB, C_, CM);
  ln_kernel<<<B_*NB, 256, 0, stream>>>(rbuf, o_x, g2, b2, o_x);
}